// Round 1
// baseline (467.700 us; speedup 1.0000x reference)
//
#include <hip/hip_runtime.h>

#define NN    50000
#define EE    1600000
#define IND   128
#define OUTD  64
#define SLOPE 0.1f

// ---------------------------------------------------------------------------
// K1: new = x @ W.T + b  (fp32 vector ALU; no fp32 MFMA on CDNA4)
//     also s_src[n] = new[n].a_src, s_dst[n] = new[n].a_dst
// Block = 256 threads, 16 nodes/block, thread = (node, 4 output dims).
// Wt in LDS transposed (pad +4 keeps float4 alignment & kills bank conflicts).
// ---------------------------------------------------------------------------
__global__ __launch_bounds__(256) void linear_kernel(
    const float* __restrict__ x, const float* __restrict__ W,
    const float* __restrict__ bias, const float* __restrict__ a,
    float* __restrict__ nbuf, float* __restrict__ s_src, float* __restrict__ s_dst)
{
    __shared__ float Wt[IND][OUTD + 4];   // Wt[k][j] = W[j*128+k]
    __shared__ float xs[16][IND + 4];     // pad 4: node rows land on distinct banks
    const int tid = threadIdx.x;

    #pragma unroll
    for (int i = 0; i < 32; ++i) {
        int idx = tid + i * 256;          // coalesced global read of W
        Wt[idx & 127][idx >> 7] = W[idx];
    }
    const int node0 = blockIdx.x * 16;
    const float4* x4 = (const float4*)(x + (size_t)node0 * IND);
    #pragma unroll
    for (int i = 0; i < 2; ++i) {
        int idx = tid + i * 256;          // 512 float4 = 16 rows x 32
        int row = idx >> 5, col = (idx & 31) * 4;
        *(float4*)&xs[row][col] = x4[idx];
    }
    __syncthreads();

    const int nl = tid >> 4;              // local node 0..15
    const int jg = tid & 15;              // dim group
    const int j0 = jg * 4;
    float4 acc = *(const float4*)&bias[j0];
    const float* xrow = xs[nl];
    #pragma unroll
    for (int k = 0; k < IND; k += 4) {
        float4 xv = *(const float4*)&xrow[k];
        float4 w0 = *(const float4*)&Wt[k + 0][j0];
        float4 w1 = *(const float4*)&Wt[k + 1][j0];
        float4 w2 = *(const float4*)&Wt[k + 2][j0];
        float4 w3 = *(const float4*)&Wt[k + 3][j0];
        acc.x = fmaf(xv.x, w0.x, acc.x); acc.y = fmaf(xv.x, w0.y, acc.y);
        acc.z = fmaf(xv.x, w0.z, acc.z); acc.w = fmaf(xv.x, w0.w, acc.w);
        acc.x = fmaf(xv.y, w1.x, acc.x); acc.y = fmaf(xv.y, w1.y, acc.y);
        acc.z = fmaf(xv.y, w1.z, acc.z); acc.w = fmaf(xv.y, w1.w, acc.w);
        acc.x = fmaf(xv.z, w2.x, acc.x); acc.y = fmaf(xv.z, w2.y, acc.y);
        acc.z = fmaf(xv.z, w2.z, acc.z); acc.w = fmaf(xv.z, w2.w, acc.w);
        acc.x = fmaf(xv.w, w3.x, acc.x); acc.y = fmaf(xv.w, w3.y, acc.y);
        acc.z = fmaf(xv.w, w3.z, acc.z); acc.w = fmaf(xv.w, w3.w, acc.w);
    }
    const int n = node0 + nl;
    *(float4*)&nbuf[(size_t)n * OUTD + j0] = acc;

    float ss = acc.x * a[j0]        + acc.y * a[j0 + 1]
             + acc.z * a[j0 + 2]    + acc.w * a[j0 + 3];
    float sd = acc.x * a[OUTD + j0]     + acc.y * a[OUTD + j0 + 1]
             + acc.z * a[OUTD + j0 + 2] + acc.w * a[OUTD + j0 + 3];
    #pragma unroll
    for (int m = 1; m < 16; m <<= 1) {   // reduce over the 16 lanes of this node
        ss += __shfl_xor(ss, m, 64);
        sd += __shfl_xor(sd, m, 64);
    }
    if (jg == 0) { s_src[n] = ss; s_dst[n] = sd; }
}

// ---------------------------------------------------------------------------
// CSR build: degree count -> wave-aggregated slot allocation -> scatter dst
// ---------------------------------------------------------------------------
__global__ __launch_bounds__(256) void degree_kernel(const int* __restrict__ ei,
                                                     int* __restrict__ deg)
{
    int e = blockIdx.x * 256 + threadIdx.x;   // E divisible by 256
    atomicAdd(&deg[ei[e]], 1);                // ei[0..E) = src
}

__global__ __launch_bounds__(256) void alloc_kernel(const int* __restrict__ deg,
                                                    int* __restrict__ cursor,
                                                    int* __restrict__ start,
                                                    int* __restrict__ cur)
{
    int n = blockIdx.x * 256 + threadIdx.x;
    int d = (n < NN) ? deg[n] : 0;
    int lane = threadIdx.x & 63;
    int sc = d;                               // wave inclusive scan
    #pragma unroll
    for (int m = 1; m < 64; m <<= 1) {
        int v = __shfl_up(sc, m, 64);
        if (lane >= m) sc += v;
    }
    int total = __shfl(sc, 63, 64);
    int ex = sc - d;                          // exclusive
    int base = 0;
    if (lane == 63) base = atomicAdd(cursor, total);  // one atomic per wave
    base = __shfl(base, 63, 64);
    if (n < NN) { start[n] = base + ex; cur[n] = base + ex; }
}

__global__ __launch_bounds__(256) void scatter_kernel(const int* __restrict__ ei,
                                                      int* __restrict__ cur,
                                                      int* __restrict__ dst_s)
{
    int e = blockIdx.x * 256 + threadIdx.x;
    int s = ei[e];
    int d = ei[EE + e];
    int slot = atomicAdd(&cur[s], 1);
    dst_s[slot] = d;
}

// ---------------------------------------------------------------------------
// K5: one wave per node, lane = output dim. No atomics; coalesced 256B row
// gathers of new[dst] (L2/L3-resident, 12.8MB). e recomputed from s_src/s_dst.
// ---------------------------------------------------------------------------
__global__ __launch_bounds__(256) void aggregate_kernel(
    const int* __restrict__ start, const int* __restrict__ cur,
    const int* __restrict__ dst_s, const float* __restrict__ nbuf,
    const float* __restrict__ s_src, const float* __restrict__ s_dst,
    float* __restrict__ out)
{
    const int wid  = threadIdx.x >> 6;
    const int lane = threadIdx.x & 63;
    const int n = blockIdx.x * 4 + wid;       // N divisible by 4
    const int beg = start[n];
    const int end = cur[n];
    const float ssn = s_src[n];
    float acc = 0.f, esum = 0.f;
    for (int i = beg; i < end; ++i) {
        int d = dst_s[i];
        float sc = ssn + s_dst[d];
        float lr = sc > 0.f ? sc : SLOPE * sc;
        float ev = __expf(lr);
        acc = fmaf(ev, nbuf[(size_t)d * OUTD + lane], acc);
        esum += ev;
    }
    out[(size_t)n * OUTD + lane] = acc / (esum + 1e-12f);
}

// ---------------------------------------------------------------------------
extern "C" void kernel_launch(void* const* d_in, const int* in_sizes, int n_in,
                              void* d_out, int out_size, void* d_ws, size_t ws_size,
                              hipStream_t stream) {
    const float* x  = (const float*)d_in[0];
    const int*   ei = (const int*)d_in[1];    // (2,E): [0..E)=src, [E..2E)=dst
    const float* W  = (const float*)d_in[2];
    const float* b  = (const float*)d_in[3];
    const float* a  = (const float*)d_in[4];
    float* out = (float*)d_out;

    // workspace layout (all 4B elems): ~20.2 MB total
    float* nbuf   = (float*)d_ws;             // N*64
    float* s_src  = nbuf + (size_t)NN * OUTD; // N
    float* s_dst  = s_src + NN;               // N
    int*   deg    = (int*)(s_dst + NN);       // N
    int*   cursor = deg + NN;                 // 1
    int*   start  = cursor + 1;               // N
    int*   cur    = start + NN;               // N
    int*   dst_s  = cur + NN;                 // E

    hipMemsetAsync(deg, 0, (NN + 1) * sizeof(int), stream);  // deg + cursor
    linear_kernel<<<NN / 16, 256, 0, stream>>>(x, W, b, a, nbuf, s_src, s_dst);
    degree_kernel<<<EE / 256, 256, 0, stream>>>(ei, deg);
    alloc_kernel<<<(NN + 255) / 256, 256, 0, stream>>>(deg, cursor, start, cur);
    scatter_kernel<<<EE / 256, 256, 0, stream>>>(ei, cur, dst_s);
    aggregate_kernel<<<NN / 4, 256, 0, stream>>>(start, cur, dst_s, nbuf,
                                                 s_src, s_dst, out);
}

// Round 2
// 357.500 us; speedup vs baseline: 1.3083x; 1.3083x over previous
//
#include <hip/hip_runtime.h>

#define NN    50000
#define EE    1600000
#define IND   128
#define OUTD  64
#define SLOPE 0.1f

// ---------------------------------------------------------------------------
// K1: new = x @ W.T + b  (fp32 vector ALU; no fp32 MFMA on CDNA4)
//     also s_src[n] = new[n].a_src, s_dst[n] = new[n].a_dst
// ---------------------------------------------------------------------------
__global__ __launch_bounds__(256) void linear_kernel(
    const float* __restrict__ x, const float* __restrict__ W,
    const float* __restrict__ bias, const float* __restrict__ a,
    float* __restrict__ nbuf, float* __restrict__ s_src, float* __restrict__ s_dst)
{
    __shared__ float Wt[IND][OUTD + 4];   // Wt[k][j] = W[j*128+k]
    __shared__ float xs[16][IND + 4];
    const int tid = threadIdx.x;

    #pragma unroll
    for (int i = 0; i < 32; ++i) {
        int idx = tid + i * 256;          // coalesced global read of W
        Wt[idx & 127][idx >> 7] = W[idx];
    }
    const int node0 = blockIdx.x * 16;
    const float4* x4 = (const float4*)(x + (size_t)node0 * IND);
    #pragma unroll
    for (int i = 0; i < 2; ++i) {
        int idx = tid + i * 256;          // 512 float4 = 16 rows x 32
        int row = idx >> 5, col = (idx & 31) * 4;
        *(float4*)&xs[row][col] = x4[idx];
    }
    __syncthreads();

    const int nl = tid >> 4;              // local node 0..15
    const int jg = tid & 15;              // dim group
    const int j0 = jg * 4;
    float4 acc = *(const float4*)&bias[j0];
    const float* xrow = xs[nl];
    #pragma unroll
    for (int k = 0; k < IND; k += 4) {
        float4 xv = *(const float4*)&xrow[k];
        float4 w0 = *(const float4*)&Wt[k + 0][j0];
        float4 w1 = *(const float4*)&Wt[k + 1][j0];
        float4 w2 = *(const float4*)&Wt[k + 2][j0];
        float4 w3 = *(const float4*)&Wt[k + 3][j0];
        acc.x = fmaf(xv.x, w0.x, acc.x); acc.y = fmaf(xv.x, w0.y, acc.y);
        acc.z = fmaf(xv.x, w0.z, acc.z); acc.w = fmaf(xv.x, w0.w, acc.w);
        acc.x = fmaf(xv.y, w1.x, acc.x); acc.y = fmaf(xv.y, w1.y, acc.y);
        acc.z = fmaf(xv.y, w1.z, acc.z); acc.w = fmaf(xv.y, w1.w, acc.w);
        acc.x = fmaf(xv.z, w2.x, acc.x); acc.y = fmaf(xv.z, w2.y, acc.y);
        acc.z = fmaf(xv.z, w2.z, acc.z); acc.w = fmaf(xv.z, w2.w, acc.w);
        acc.x = fmaf(xv.w, w3.x, acc.x); acc.y = fmaf(xv.w, w3.y, acc.y);
        acc.z = fmaf(xv.w, w3.z, acc.z); acc.w = fmaf(xv.w, w3.w, acc.w);
    }
    const int n = node0 + nl;
    *(float4*)&nbuf[(size_t)n * OUTD + j0] = acc;

    float ss = acc.x * a[j0]        + acc.y * a[j0 + 1]
             + acc.z * a[j0 + 2]    + acc.w * a[j0 + 3];
    float sd = acc.x * a[OUTD + j0]     + acc.y * a[OUTD + j0 + 1]
             + acc.z * a[OUTD + j0 + 2] + acc.w * a[OUTD + j0 + 3];
    #pragma unroll
    for (int m = 1; m < 16; m <<= 1) {
        ss += __shfl_xor(ss, m, 64);
        sd += __shfl_xor(sd, m, 64);
    }
    if (jg == 0) { s_src[n] = ss; s_dst[n] = sd; }
}

// ---------------------------------------------------------------------------
// CSR build: degree count -> wave-aggregated slot allocation -> scatter dst
// int4-vectorized: 4 edges/thread, 4 independent atomics in flight.
// ---------------------------------------------------------------------------
__global__ __launch_bounds__(256) void degree_kernel(const int* __restrict__ ei,
                                                     int* __restrict__ deg)
{
    int t = blockIdx.x * 256 + threadIdx.x;
    if (t * 4 >= EE) return;
    int4 s4 = ((const int4*)ei)[t];
    atomicAdd(&deg[s4.x], 1);
    atomicAdd(&deg[s4.y], 1);
    atomicAdd(&deg[s4.z], 1);
    atomicAdd(&deg[s4.w], 1);
}

__global__ __launch_bounds__(256) void alloc_kernel(const int* __restrict__ deg,
                                                    int* __restrict__ cursor,
                                                    int* __restrict__ start,
                                                    int* __restrict__ cur)
{
    int n = blockIdx.x * 256 + threadIdx.x;
    int d = (n < NN) ? deg[n] : 0;
    int lane = threadIdx.x & 63;
    int sc = d;                               // wave inclusive scan
    #pragma unroll
    for (int m = 1; m < 64; m <<= 1) {
        int v = __shfl_up(sc, m, 64);
        if (lane >= m) sc += v;
    }
    int total = __shfl(sc, 63, 64);
    int ex = sc - d;                          // exclusive
    int base = 0;
    if (lane == 63) base = atomicAdd(cursor, total);  // one atomic per wave
    base = __shfl(base, 63, 64);
    if (n < NN) { start[n] = base + ex; cur[n] = base + ex; }
}

__global__ __launch_bounds__(256) void scatter_kernel(const int* __restrict__ ei,
                                                      int* __restrict__ cur,
                                                      int* __restrict__ dst_s)
{
    int t = blockIdx.x * 256 + threadIdx.x;
    if (t * 4 >= EE) return;
    int4 s4 = ((const int4*)ei)[t];
    int4 d4 = ((const int4*)(ei + EE))[t];
    int p0 = atomicAdd(&cur[s4.x], 1);
    int p1 = atomicAdd(&cur[s4.y], 1);
    int p2 = atomicAdd(&cur[s4.z], 1);
    int p3 = atomicAdd(&cur[s4.w], 1);
    dst_s[p0] = d4.x;
    dst_s[p1] = d4.y;
    dst_s[p2] = d4.z;
    dst_s[p3] = d4.w;
}

// ---------------------------------------------------------------------------
// K5: one wave per node, lane = output dim.
// Batched: 64 dst indices per coalesced load, lane-parallel exp, then
// 8-deep-unrolled row gathers (8 x 256B in flight per wave).
// ---------------------------------------------------------------------------
__global__ __launch_bounds__(256) void aggregate_kernel(
    const int* __restrict__ start, const int* __restrict__ cur,
    const int* __restrict__ dst_s, const float* __restrict__ nbuf,
    const float* __restrict__ s_src, const float* __restrict__ s_dst,
    float* __restrict__ out)
{
    const int wid  = threadIdx.x >> 6;
    const int lane = threadIdx.x & 63;
    const int n = blockIdx.x * 4 + wid;       // N divisible by 4
    const int beg = start[n];
    const int len = cur[n] - beg;
    const float ssn = s_src[n];
    float acc = 0.f, esuml = 0.f;

    for (int c = 0; c < len; c += 64) {
        const int m = min(64, len - c);
        int d = 0; float ev = 0.f;
        if (lane < m) {                       // one coalesced index load
            d = dst_s[beg + c + lane];
            float sc = ssn + s_dst[d];        // lane-parallel score+exp
            float lr = sc > 0.f ? sc : SLOPE * sc;
            ev = __expf(lr);
        }
        esuml += ev;

        int i = 0;
        for (; i + 8 <= m; i += 8) {
            int d0 = __shfl(d, i + 0, 64); float e0 = __shfl(ev, i + 0, 64);
            int d1 = __shfl(d, i + 1, 64); float e1 = __shfl(ev, i + 1, 64);
            int d2 = __shfl(d, i + 2, 64); float e2 = __shfl(ev, i + 2, 64);
            int d3 = __shfl(d, i + 3, 64); float e3 = __shfl(ev, i + 3, 64);
            int d4 = __shfl(d, i + 4, 64); float e4 = __shfl(ev, i + 4, 64);
            int d5 = __shfl(d, i + 5, 64); float e5 = __shfl(ev, i + 5, 64);
            int d6 = __shfl(d, i + 6, 64); float e6 = __shfl(ev, i + 6, 64);
            int d7 = __shfl(d, i + 7, 64); float e7 = __shfl(ev, i + 7, 64);
            float v0 = nbuf[(size_t)d0 * OUTD + lane];
            float v1 = nbuf[(size_t)d1 * OUTD + lane];
            float v2 = nbuf[(size_t)d2 * OUTD + lane];
            float v3 = nbuf[(size_t)d3 * OUTD + lane];
            float v4 = nbuf[(size_t)d4 * OUTD + lane];
            float v5 = nbuf[(size_t)d5 * OUTD + lane];
            float v6 = nbuf[(size_t)d6 * OUTD + lane];
            float v7 = nbuf[(size_t)d7 * OUTD + lane];
            acc = fmaf(e0, v0, acc); acc = fmaf(e1, v1, acc);
            acc = fmaf(e2, v2, acc); acc = fmaf(e3, v3, acc);
            acc = fmaf(e4, v4, acc); acc = fmaf(e5, v5, acc);
            acc = fmaf(e6, v6, acc); acc = fmaf(e7, v7, acc);
        }
        for (; i < m; ++i) {
            int dd = __shfl(d, i, 64);
            float ee = __shfl(ev, i, 64);
            acc = fmaf(ee, nbuf[(size_t)dd * OUTD + lane], acc);
        }
    }

    #pragma unroll
    for (int msk = 1; msk < 64; msk <<= 1)
        esuml += __shfl_xor(esuml, msk, 64);
    out[(size_t)n * OUTD + lane] = acc / (esuml + 1e-12f);
}

// ---------------------------------------------------------------------------
extern "C" void kernel_launch(void* const* d_in, const int* in_sizes, int n_in,
                              void* d_out, int out_size, void* d_ws, size_t ws_size,
                              hipStream_t stream) {
    const float* x  = (const float*)d_in[0];
    const int*   ei = (const int*)d_in[1];    // (2,E): [0..E)=src, [E..2E)=dst
    const float* W  = (const float*)d_in[2];
    const float* b  = (const float*)d_in[3];
    const float* a  = (const float*)d_in[4];
    float* out = (float*)d_out;

    float* nbuf   = (float*)d_ws;             // N*64
    float* s_src  = nbuf + (size_t)NN * OUTD; // N
    float* s_dst  = s_src + NN;               // N
    int*   deg    = (int*)(s_dst + NN);       // N
    int*   cursor = deg + NN;                 // 1
    int*   start  = cursor + 1;               // N
    int*   cur    = start + NN;               // N
    int*   dst_s  = cur + NN;                 // E

    hipMemsetAsync(deg, 0, (NN + 1) * sizeof(int), stream);  // deg + cursor
    linear_kernel<<<NN / 16, 256, 0, stream>>>(x, W, b, a, nbuf, s_src, s_dst);
    degree_kernel<<<(EE / 4 + 255) / 256, 256, 0, stream>>>(ei, deg);
    alloc_kernel<<<(NN + 255) / 256, 256, 0, stream>>>(deg, cursor, start, cur);
    scatter_kernel<<<(EE / 4 + 255) / 256, 256, 0, stream>>>(ei, cur, dst_s);
    aggregate_kernel<<<NN / 4, 256, 0, stream>>>(start, cur, dst_s, nbuf,
                                                 s_src, s_dst, out);
}

// Round 3
// 210.920 us; speedup vs baseline: 2.2174x; 1.6949x over previous
//
#include <hip/hip_runtime.h>

#define NN    50000
#define EE    1600000
#define IND   128
#define OUTD  64
#define SLOPE 0.1f

#define BW     128                 // nodes per bucket (src >> 7)
#define NB     391                 // ceil(NN / BW)
#define NBLK   250                 // chunk blocks; EE/NBLK = 6400 edges/block
#define CHUNK  (EE / NBLK)         // 6400

// ---------------------------------------------------------------------------
// K1: new = x @ W.T + b  (fp32 vector ALU; no fp32 MFMA on CDNA4)
//     also s_src[n] = new[n].a_src, s_dst[n] = new[n].a_dst
// ---------------------------------------------------------------------------
__global__ __launch_bounds__(256) void linear_kernel(
    const float* __restrict__ x, const float* __restrict__ W,
    const float* __restrict__ bias, const float* __restrict__ a,
    float* __restrict__ nbuf, float* __restrict__ s_src, float* __restrict__ s_dst)
{
    __shared__ float Wt[IND][OUTD + 4];   // Wt[k][j] = W[j*128+k]
    __shared__ float xs[16][IND + 4];
    const int tid = threadIdx.x;

    #pragma unroll
    for (int i = 0; i < 32; ++i) {
        int idx = tid + i * 256;          // coalesced global read of W
        Wt[idx & 127][idx >> 7] = W[idx];
    }
    const int node0 = blockIdx.x * 16;
    const float4* x4 = (const float4*)(x + (size_t)node0 * IND);
    #pragma unroll
    for (int i = 0; i < 2; ++i) {
        int idx = tid + i * 256;          // 512 float4 = 16 rows x 32
        int row = idx >> 5, col = (idx & 31) * 4;
        *(float4*)&xs[row][col] = x4[idx];
    }
    __syncthreads();

    const int nl = tid >> 4;              // local node 0..15
    const int jg = tid & 15;              // dim group
    const int j0 = jg * 4;
    float4 acc = *(const float4*)&bias[j0];
    const float* xrow = xs[nl];
    #pragma unroll
    for (int k = 0; k < IND; k += 4) {
        float4 xv = *(const float4*)&xrow[k];
        float4 w0 = *(const float4*)&Wt[k + 0][j0];
        float4 w1 = *(const float4*)&Wt[k + 1][j0];
        float4 w2 = *(const float4*)&Wt[k + 2][j0];
        float4 w3 = *(const float4*)&Wt[k + 3][j0];
        acc.x = fmaf(xv.x, w0.x, acc.x); acc.y = fmaf(xv.x, w0.y, acc.y);
        acc.z = fmaf(xv.x, w0.z, acc.z); acc.w = fmaf(xv.x, w0.w, acc.w);
        acc.x = fmaf(xv.y, w1.x, acc.x); acc.y = fmaf(xv.y, w1.y, acc.y);
        acc.z = fmaf(xv.y, w1.z, acc.z); acc.w = fmaf(xv.y, w1.w, acc.w);
        acc.x = fmaf(xv.z, w2.x, acc.x); acc.y = fmaf(xv.z, w2.y, acc.y);
        acc.z = fmaf(xv.z, w2.z, acc.z); acc.w = fmaf(xv.z, w2.w, acc.w);
        acc.x = fmaf(xv.w, w3.x, acc.x); acc.y = fmaf(xv.w, w3.y, acc.y);
        acc.z = fmaf(xv.w, w3.z, acc.z); acc.w = fmaf(xv.w, w3.w, acc.w);
    }
    const int n = node0 + nl;
    *(float4*)&nbuf[(size_t)n * OUTD + j0] = acc;

    float ss = acc.x * a[j0]        + acc.y * a[j0 + 1]
             + acc.z * a[j0 + 2]    + acc.w * a[j0 + 3];
    float sd = acc.x * a[OUTD + j0]     + acc.y * a[OUTD + j0 + 1]
             + acc.z * a[OUTD + j0 + 2] + acc.w * a[OUTD + j0 + 3];
    #pragma unroll
    for (int m = 1; m < 16; m <<= 1) {
        ss += __shfl_xor(ss, m, 64);
        sd += __shfl_xor(sd, m, 64);
    }
    if (jg == 0) { s_src[n] = ss; s_dst[n] = sd; }
}

// ---------------------------------------------------------------------------
// CSR build v2: two-level counting sort. All hot atomics are LDS; global
// writes are bucket-contiguous (kills the 102MB write amplification).
// ---------------------------------------------------------------------------
__global__ __launch_bounds__(256) void hist_kernel(const int* __restrict__ ei,
                                                   int* __restrict__ bhist)
{
    __shared__ int h[NB];
    for (int i = threadIdx.x; i < NB; i += 256) h[i] = 0;
    __syncthreads();
    const int base = blockIdx.x * CHUNK;
    for (int i = threadIdx.x; i < CHUNK; i += 256)
        atomicAdd(&h[ei[base + i] >> 7], 1);
    __syncthreads();
    for (int i = threadIdx.x; i < NB; i += 256)
        if (h[i]) atomicAdd(&bhist[i], h[i]);
}

__global__ __launch_bounds__(512) void scan_kernel(const int* __restrict__ bhist,
                                                   int* __restrict__ bstart,
                                                   int* __restrict__ gcur)
{
    __shared__ int h[NB], ps[NB + 1];
    const int t = threadIdx.x;
    if (t < NB) h[t] = bhist[t];
    __syncthreads();
    if (t == 0) {
        int run = 0;
        for (int b = 0; b < NB; ++b) { ps[b] = run; run += h[b]; }
        ps[NB] = run;
    }
    __syncthreads();
    if (t < NB) { bstart[t] = ps[t]; gcur[t] = ps[t]; }
    if (t == 0) bstart[NB] = ps[NB];
}

__global__ __launch_bounds__(256) void binscatter_kernel(const int* __restrict__ ei,
                                                         int* __restrict__ gcur,
                                                         unsigned* __restrict__ ebuf)
{
    __shared__ int h[NB];                 // local hist -> global-base cursors
    for (int i = threadIdx.x; i < NB; i += 256) h[i] = 0;
    __syncthreads();
    const int base = blockIdx.x * CHUNK;
    for (int i = threadIdx.x; i < CHUNK; i += 256)
        atomicAdd(&h[ei[base + i] >> 7], 1);
    __syncthreads();
    for (int i = threadIdx.x; i < NB; i += 256) {
        int c = h[i];
        if (c) h[i] = atomicAdd(&gcur[i], c);   // reserve contiguous run
    }
    __syncthreads();
    for (int i = threadIdx.x; i < CHUNK; i += 256) {
        int s = ei[base + i];
        int d = ei[EE + base + i];
        int pos = atomicAdd(&h[s >> 7], 1);     // LDS cursor
        ebuf[pos] = ((unsigned)s << 16) | (unsigned)d;   // both < 65536
    }
}

__global__ __launch_bounds__(256) void finescatter_kernel(
    const unsigned* __restrict__ ebuf, const int* __restrict__ bstart,
    int* __restrict__ start, int* __restrict__ endc, int* __restrict__ dst_s)
{
    __shared__ int h[BW + 1];
    __shared__ int cur[BW];
    const int b  = blockIdx.x;
    const int lo = bstart[b], hi = bstart[b + 1];
    const int cnt = hi - lo;
    for (int i = threadIdx.x; i < BW; i += 256) h[i] = 0;
    __syncthreads();
    for (int i = threadIdx.x; i < cnt; i += 256)
        atomicAdd(&h[(ebuf[lo + i] >> 16) & (BW - 1)], 1);
    __syncthreads();
    if (threadIdx.x == 0) {                     // prefix over 128 in LDS
        int run = lo;
        for (int i = 0; i < BW; ++i) { int c = h[i]; h[i] = run; run += c; }
        h[BW] = run;                            // == hi
    }
    __syncthreads();
    const int n0 = b * BW;
    for (int i = threadIdx.x; i < BW; i += 256) {
        cur[i] = h[i];
        int n = n0 + i;
        if (n < NN) { start[n] = h[i]; endc[n] = h[i + 1]; }
    }
    __syncthreads();
    for (int i = threadIdx.x; i < cnt; i += 256) {
        unsigned p = ebuf[lo + i];
        int pos = atomicAdd(&cur[(p >> 16) & (BW - 1)], 1);
        dst_s[pos] = (int)(p & 0xFFFFu);        // contiguous 16KB region/block
    }
}

// ---------------------------------------------------------------------------
// K5: one wave per node, lane = output dim. Batched: 64 indices/coalesced
// load, lane-parallel exp, 8-deep-unrolled row gathers in flight.
// ---------------------------------------------------------------------------
__global__ __launch_bounds__(256) void aggregate_kernel(
    const int* __restrict__ start, const int* __restrict__ endc,
    const int* __restrict__ dst_s, const float* __restrict__ nbuf,
    const float* __restrict__ s_src, const float* __restrict__ s_dst,
    float* __restrict__ out)
{
    const int wid  = threadIdx.x >> 6;
    const int lane = threadIdx.x & 63;
    const int n = blockIdx.x * 4 + wid;       // N divisible by 4
    const int beg = start[n];
    const int len = endc[n] - beg;
    const float ssn = s_src[n];
    float acc = 0.f, esuml = 0.f;

    for (int c = 0; c < len; c += 64) {
        const int m = min(64, len - c);
        int d = 0; float ev = 0.f;
        if (lane < m) {                       // one coalesced index load
            d = dst_s[beg + c + lane];
            float sc = ssn + s_dst[d];        // lane-parallel score+exp
            float lr = sc > 0.f ? sc : SLOPE * sc;
            ev = __expf(lr);
        }
        esuml += ev;

        int i = 0;
        for (; i + 8 <= m; i += 8) {
            int d0 = __shfl(d, i + 0, 64); float e0 = __shfl(ev, i + 0, 64);
            int d1 = __shfl(d, i + 1, 64); float e1 = __shfl(ev, i + 1, 64);
            int d2 = __shfl(d, i + 2, 64); float e2 = __shfl(ev, i + 2, 64);
            int d3 = __shfl(d, i + 3, 64); float e3 = __shfl(ev, i + 3, 64);
            int d4 = __shfl(d, i + 4, 64); float e4 = __shfl(ev, i + 4, 64);
            int d5 = __shfl(d, i + 5, 64); float e5 = __shfl(ev, i + 5, 64);
            int d6 = __shfl(d, i + 6, 64); float e6 = __shfl(ev, i + 6, 64);
            int d7 = __shfl(d, i + 7, 64); float e7 = __shfl(ev, i + 7, 64);
            float v0 = nbuf[(size_t)d0 * OUTD + lane];
            float v1 = nbuf[(size_t)d1 * OUTD + lane];
            float v2 = nbuf[(size_t)d2 * OUTD + lane];
            float v3 = nbuf[(size_t)d3 * OUTD + lane];
            float v4 = nbuf[(size_t)d4 * OUTD + lane];
            float v5 = nbuf[(size_t)d5 * OUTD + lane];
            float v6 = nbuf[(size_t)d6 * OUTD + lane];
            float v7 = nbuf[(size_t)d7 * OUTD + lane];
            acc = fmaf(e0, v0, acc); acc = fmaf(e1, v1, acc);
            acc = fmaf(e2, v2, acc); acc = fmaf(e3, v3, acc);
            acc = fmaf(e4, v4, acc); acc = fmaf(e5, v5, acc);
            acc = fmaf(e6, v6, acc); acc = fmaf(e7, v7, acc);
        }
        for (; i < m; ++i) {
            int dd = __shfl(d, i, 64);
            float ee = __shfl(ev, i, 64);
            acc = fmaf(ee, nbuf[(size_t)dd * OUTD + lane], acc);
        }
    }

    #pragma unroll
    for (int msk = 1; msk < 64; msk <<= 1)
        esuml += __shfl_xor(esuml, msk, 64);
    out[(size_t)n * OUTD + lane] = acc / (esuml + 1e-12f);
}

// ---------------------------------------------------------------------------
extern "C" void kernel_launch(void* const* d_in, const int* in_sizes, int n_in,
                              void* d_out, int out_size, void* d_ws, size_t ws_size,
                              hipStream_t stream) {
    const float* x  = (const float*)d_in[0];
    const int*   ei = (const int*)d_in[1];    // (2,E): [0..E)=src, [E..2E)=dst
    const float* W  = (const float*)d_in[2];
    const float* b  = (const float*)d_in[3];
    const float* a  = (const float*)d_in[4];
    float* out = (float*)d_out;

    // workspace layout (4B elems), ~27MB total
    float*    nbuf   = (float*)d_ws;              // N*64
    float*    s_src  = nbuf + (size_t)NN * OUTD;  // N
    float*    s_dst  = s_src + NN;                // N
    int*      bhist  = (int*)(s_dst + NN);        // NB
    int*      bstart = bhist + NB;                // NB+1
    int*      gcur   = bstart + NB + 1;           // NB
    int*      start  = gcur + NB;                 // N
    int*      endc   = start + NN;                // N
    unsigned* ebuf   = (unsigned*)(endc + NN);    // E
    int*      dst_s  = (int*)(ebuf + EE);         // E

    hipMemsetAsync(bhist, 0, NB * sizeof(int), stream);
    linear_kernel<<<NN / 16, 256, 0, stream>>>(x, W, b, a, nbuf, s_src, s_dst);
    hist_kernel<<<NBLK, 256, 0, stream>>>(ei, bhist);
    scan_kernel<<<1, 512, 0, stream>>>(bhist, bstart, gcur);
    binscatter_kernel<<<NBLK, 256, 0, stream>>>(ei, gcur, ebuf);
    finescatter_kernel<<<NB, 256, 0, stream>>>(ebuf, bstart, start, endc, dst_s);
    aggregate_kernel<<<NN / 4, 256, 0, stream>>>(start, endc, dst_s, nbuf,
                                                 s_src, s_dst, out);
}